// Round 9
// baseline (260.885 us; speedup 1.0000x reference)
//
#include <hip/hip_runtime.h>

#define EPS 1e-10f

// Problem shape (fixed by setup_inputs): [B, C, F, T] = [32, 2, 257, 2000]
constexpr int B    = 32;
constexpr int CF   = 514;   // C*F = 2*257
constexpr int T    = 2000;
constexpr int T4   = T / 4; // 500 float4 per row
constexpr int ROWS = B * CF;   // 16448
constexpr int RPB  = 8;        // rows per k_norm block -> 2056 blocks

typedef float f4_native __attribute__((ext_vector_type(4)));

// ---------------------------------------------------------------------------
// Kernel 1: frame_mean[b][t] = mean_{cf} x[b][cf][t]   (proven rounds 2-8)
// block = (64 t-lanes, 8 cf-groups); coalesced 256B/wave reads; LDS reduce.
// Side effect k_norm exploits: x (131.6 MB) is L3-resident afterwards.
// ---------------------------------------------------------------------------
__global__ __launch_bounds__(512) void k_frame_mean(const float* __restrict__ x,
                                                    float* __restrict__ fm) {
    __shared__ float lds[8][64];
    const int t  = blockIdx.x * 64 + threadIdx.x;   // T=2000 < 32*64=2048
    const int b  = blockIdx.y;
    const int ty = threadIdx.y;

    float s = 0.0f;
    if (t < T) {
        const float* p = x + ((size_t)b * CF + ty) * T + t;
        #pragma unroll 4
        for (int cf = ty; cf < CF; cf += 8) {
            s += *p;
            p += 8 * (size_t)T;
        }
    }
    lds[ty][threadIdx.x] = s;
    __syncthreads();
    if (ty == 0 && t < T) {
        float tot = lds[0][threadIdx.x];
        #pragma unroll
        for (int k = 1; k < 8; ++k) tot += lds[k][threadIdx.x];
        fm[(size_t)b * T + t] = tot / (float)CF;   // IEEE, matches jnp.mean
    }
}

// ---------------------------------------------------------------------------
// Kernel 2: parallel affine EMA scan (proven round 4, ~4 us). One wave per
// batch; lane l owns t in [32l, 32l+32). Exact per-t a = min((t-1)/(t+1), α).
// ---------------------------------------------------------------------------
__global__ __launch_bounds__(256) void k_scan_par(const float* __restrict__ fm,
                                                  const int* __restrict__ d_sl,
                                                  float* __restrict__ mu_out) {
    const int wave = threadIdx.x >> 6;           // 0..3
    const int lane = threadIdx.x & 63;
    const int b    = blockIdx.x * 4 + wave;      // grid 8 -> b in [0,32)
    if (b >= B) return;

    const int sl = d_sl[0];
    const float alpha = (float)((double)(sl - 1) / (double)(sl + 1));

    const float* __restrict__ m = fm + (size_t)b * T;
    float* __restrict__ o = mu_out + (size_t)b * T;

    const int t0 = lane * 32;                    // lanes 0..61 full, 62 partial, 63 empty

    float v[32];
    if (t0 + 32 <= T) {
        #pragma unroll
        for (int j = 0; j < 8; ++j)
            *(float4*)(v + 4 * j) = *(const float4*)(m + t0 + 4 * j);
    } else {
        #pragma unroll
        for (int j = 0; j < 32; ++j)
            v[j] = (t0 + j < T) ? m[t0 + j] : 0.0f;
    }

    // Compose chunk into affine (A, Bv): mu_out = A*mu_in + Bv.
    float A = 1.0f, Bv = 0.0f;
    #pragma unroll
    for (int i = 0; i < 32; ++i) {
        const int t = t0 + i;
        const float ft = (float)t;
        const float a  = (t < T) ? fminf((ft - 1.0f) / (ft + 1.0f), alpha) : 1.0f;
        const float vv = (t < T) ? v[i] : 0.0f;
        Bv = a * Bv + (1.0f - a) * vv;
        A  = a * A;
    }

    // Inclusive wave scan of affine pairs (later ∘ earlier).
    float pA = A, pB = Bv;
    #pragma unroll
    for (int d = 1; d < 64; d <<= 1) {
        const float uA = __shfl_up(pA, d);
        const float uB = __shfl_up(pB, d);
        if (lane >= d) {
            pB = pA * uB + pB;
            pA = pA * uA;
        }
    }

    // Incoming mu = exclusive prefix applied to mu0=0 -> B_excl.
    const float eB = __shfl_up(pB, 1);
    float mu = (lane == 0) ? 0.0f : eB;

    // Serial recompute with true incoming mu; store.
    #pragma unroll
    for (int i = 0; i < 32; ++i) {
        const int t = t0 + i;
        if (t < T) {
            const float ft = (float)t;
            const float a  = fminf((ft - 1.0f) / (ft + 1.0f), alpha);
            mu = a * mu + (1.0f - a) * v[i];
            o[t] = mu;
        }
    }
}

// ---------------------------------------------------------------------------
// Kernel 3: out = x / (mu + EPS).
// Round-9 restructure per Guideline 11: 2056 blocks (8 blocks/CU) x 256 thr,
// each block owns 8 CONTIGUOUS rows (256 KB span of x); each thread does 16
// independent float4 div+store ops fully unrolled -> deep memory-level
// parallelism without the 32896-block workgroup-launch churn of rounds 2-8
// and without round 6's 4-blocks/CU latency trap. NT stores keep the out
// writes from evicting L3-resident x.
// ---------------------------------------------------------------------------
__global__ __launch_bounds__(256) void k_norm(const float4* __restrict__ x,
                                              const float4* __restrict__ mu4,
                                              f4_native* __restrict__ out) {
    const int tid  = threadIdx.x;
    const int row0 = blockIdx.x * RPB;

    #pragma unroll
    for (int r = 0; r < RPB; ++r) {
        const int row = row0 + r;          // b*CF + cf
        const int b   = row / CF;
        const size_t base = (size_t)row * T4;
        const size_t mub  = (size_t)b * T4;

        {   // t4 = tid (0..255)
            const float4 v = x[base + tid];
            const float4 m = mu4[mub + tid];
            f4_native o;
            o.x = v.x / (m.x + EPS);
            o.y = v.y / (m.y + EPS);
            o.z = v.z / (m.z + EPS);
            o.w = v.w / (m.w + EPS);
            __builtin_nontemporal_store(o, &out[base + tid]);
        }
        if (tid < T4 - 256) {   // t4 = 256 + tid (256..499)
            const float4 v = x[base + 256 + tid];
            const float4 m = mu4[mub + 256 + tid];
            f4_native o;
            o.x = v.x / (m.x + EPS);
            o.y = v.y / (m.y + EPS);
            o.z = v.z / (m.z + EPS);
            o.w = v.w / (m.w + EPS);
            __builtin_nontemporal_store(o, &out[base + 256 + tid]);
        }
    }
}

// ---------------------------------------------------------------------------
extern "C" void kernel_launch(void* const* d_in, const int* in_sizes, int n_in,
                              void* d_out, int out_size, void* d_ws, size_t ws_size,
                              hipStream_t stream) {
    const float* x    = (const float*)d_in[0];
    const int*   d_sl = (const int*)d_in[1];
    float*       out  = (float*)d_out;

    // workspace layout: fm [B*T] floats, mu [B*T] floats  (512 KB total)
    float* fm = (float*)d_ws;
    float* mu = fm + (size_t)B * T;

    // Kernel 1: per-frame mean
    {
        dim3 grid((T + 63) / 64, B);
        dim3 block(64, 8);
        k_frame_mean<<<grid, block, 0, stream>>>(x, fm);
    }
    // Kernel 2: parallel EMA scan
    {
        k_scan_par<<<8, 256, 0, stream>>>(fm, d_sl, mu);
    }
    // Kernel 3: normalize (grid-strided rows, NT stores)
    {
        k_norm<<<dim3(ROWS / RPB), dim3(256), 0, stream>>>(
            (const float4*)x, (const float4*)mu, (f4_native*)out);
    }
}